// Round 11
// baseline (497.225 us; speedup 1.0000x reference)
//
#include <hip/hip_runtime.h>
#include <math.h>

#define BB 16
#define DMODEL 2048
#define NHEAD 32
#define SKV 4096
#define HDIM 64
#define BH (BB*NHEAD)   /* 512 */
#define NSTRIP 16

typedef float f4 __attribute__((ext_vector_type(4)));

// ---------------------------------------------------------------------------
// partial GEMM: part[tile_y][b][o] = sum_{i in tile of 64} src[b][i]*W[i][o]
// grid (2, 32, nmat), block 256, thread owns 4 consecutive o-columns.
// ---------------------------------------------------------------------------
__global__ __launch_bounds__(256) void gemm_part(
    const float* __restrict__ src,
    const float* __restrict__ Wa, const float* __restrict__ Wb,
    const float* __restrict__ Wc,
    float* __restrict__ pa, float* __restrict__ pb, float* __restrict__ pc) {
  const float* W = (blockIdx.z == 0) ? Wa : ((blockIdx.z == 1) ? Wb : Wc);
  float* part    = (blockIdx.z == 0) ? pa : ((blockIdx.z == 1) ? pb : pc);
  __shared__ float xs[16][64];
  int tid = threadIdx.x;
  int i0 = blockIdx.y * 64;
  int o  = blockIdx.x * 1024 + tid * 4;
  {
    int t = tid * 4;
    int b = t >> 6, i = t & 63;
    *(f4*)&xs[b][i] = *(const f4*)&src[b * DMODEL + i0 + i];
  }
  __syncthreads();
  f4 acc[16];
#pragma unroll
  for (int b = 0; b < 16; ++b) acc[b] = (f4)0.f;
#pragma unroll 8
  for (int i = 0; i < 64; ++i) {
    f4 w = *(const f4*)&W[(size_t)(i0 + i) * DMODEL + o];
#pragma unroll
    for (int b = 0; b < 16; ++b) acc[b] += xs[b][i] * w;
  }
  float* p = part + (size_t)blockIdx.y * (16 * DMODEL) + o;
#pragma unroll
  for (int b = 0; b < 16; ++b) *(f4*)&p[b * DMODEL] = acc[b];
}

// ---------------------------------------------------------------------------
// reduce partials over 32 tiles + bias -> dst.  grid (128, nmat)
// ---------------------------------------------------------------------------
__global__ __launch_bounds__(256) void gemm_reduce(
    const float* __restrict__ pa, const float* __restrict__ pb,
    const float* __restrict__ pc,
    const float* __restrict__ ba, const float* __restrict__ bb,
    const float* __restrict__ bc,
    float* __restrict__ da, float* __restrict__ db, float* __restrict__ dc) {
  const float* p    = (blockIdx.y == 0) ? pa : ((blockIdx.y == 1) ? pb : pc);
  const float* bias = (blockIdx.y == 0) ? ba : ((blockIdx.y == 1) ? bb : bc);
  float* dst        = (blockIdx.y == 0) ? da : ((blockIdx.y == 1) ? db : dc);
  int idx = blockIdx.x * 256 + threadIdx.x;
  float s = bias[idx & (DMODEL - 1)];
#pragma unroll 8
  for (int t = 0; t < 32; ++t) s += p[(size_t)t * (16 * DMODEL) + idx];
  dst[idx] = s;
}

// ---------------------------------------------------------------------------
// K copy + scores. PLAIN loads (L2-assisted) + NT stores (no write-allocate
// pollution) -- single-variable A/B vs R9's nt/nt. Stores UNNORMALIZED probs
// exp(s - M_strip) to scores via LDS (coalesced), per-strip (M, Sexp) to
// pstat. Block = 256 rows of one (b,h); q pre-scaled by 1/8.
// ---------------------------------------------------------------------------
__global__ __launch_bounds__(256) void k_copy_scores(
    const float* __restrict__ cacheK, const float* __restrict__ knew,
    const float* __restrict__ qv, const int* __restrict__ last_pos,
    float* __restrict__ outK, float* __restrict__ scores,
    float* __restrict__ pstat) {
  int bh = blockIdx.x >> 4;
  int blk = blockIdx.x & 15;
  int j0 = blk << 8;
  int b = bh >> 5;
  int lp = last_pos[b];
  int tid = threadIdx.x;
  int wave = tid >> 6, lane = tid & 63, q4 = lane >> 4, l16 = lane & 15;
  int rbase = wave * 4 + q4;
  const f4 qf = ((const f4*)(qv + bh * HDIM))[l16] * 0.125f;
  const f4 kn = ((const f4*)(knew + bh * HDIM))[l16];
  size_t base = ((size_t)bh * SKV + j0 + rbase) * 16 + l16;
  const f4* K4 = (const f4*)cacheK + base;
  f4* O4 = (f4*)outK + base;
  float fv[16];
#pragma unroll
  for (int t = 0; t < 16; ++t) {
    int j = j0 + rbase + t * 16;
    f4 kv = K4[t * 256];                       // plain load
    if (j == lp) kv = kn;
    __builtin_nontemporal_store(kv, &O4[t * 256]);
    float p = qf.x * kv.x + qf.y * kv.y + qf.z * kv.z + qf.w * kv.w;
    p += __shfl_xor(p, 1);
    p += __shfl_xor(p, 2);
    p += __shfl_xor(p, 4);
    p += __shfl_xor(p, 8);
    fv[t] = (j <= lp) ? p : -1e30f;
  }
  float m = fv[0];
#pragma unroll
  for (int t = 1; t < 16; ++t) m = fmaxf(m, fv[t]);
  m = fmaxf(m, __shfl_xor(m, 16));
  m = fmaxf(m, __shfl_xor(m, 32));
  __shared__ float lm[4], ls[4], sp[256];
  if (lane == 0) lm[wave] = m;
  __syncthreads();
  float M = fmaxf(fmaxf(lm[0], lm[1]), fmaxf(lm[2], lm[3]));
  float se = 0.f;
#pragma unroll
  for (int t = 0; t < 16; ++t) {
    float e = __expf(fv[t] - M);
    se += e;
    if (l16 == 0) sp[rbase + t * 16] = e;   // 0 for masked rows
  }
  se += __shfl_xor(se, 16);
  se += __shfl_xor(se, 32);
  if (lane == 0) ls[wave] = se;
  __syncthreads();
  scores[(size_t)bh * SKV + j0 + tid] = sp[tid];   // coalesced 1KB store
  if (tid == 0) {
    pstat[(bh * 16 + blk) * 2 + 0] = M;
    pstat[(bh * 16 + blk) * 2 + 1] = ls[0] + ls[1] + ls[2] + ls[3];
  }
}

// ---------------------------------------------------------------------------
// V copy + PV accumulate. Plain loads + NT stores. Cheap prelude (no
// per-element exp): stage unnormalized probs in LDS, one scalar alpha.
// Per-strip record = alpha * sum (no atomics).
// ---------------------------------------------------------------------------
__global__ __launch_bounds__(256) void v_copy_pv(
    const float* __restrict__ cacheV, const float* __restrict__ vnew,
    const float* __restrict__ scores, const float* __restrict__ pstat,
    const int* __restrict__ last_pos,
    float* __restrict__ outV, float* __restrict__ prec) {
  __shared__ float sm[16], ss[16], sp[256];
  __shared__ float part[4][64];
  int bh = blockIdx.x >> 4;
  int blk = blockIdx.x & 15;
  int j0 = blk << 8;
  int b = bh >> 5;
  int lp = last_pos[b];
  int tid = threadIdx.x;
  if (tid < 16) {
    sm[tid] = pstat[(bh * 16 + tid) * 2 + 0];
    ss[tid] = pstat[(bh * 16 + tid) * 2 + 1];
  }
  sp[tid] = scores[(size_t)bh * SKV + j0 + tid];   // unnormalized probs
  __syncthreads();
  float M = sm[0];
#pragma unroll
  for (int i = 1; i < 16; ++i) M = fmaxf(M, sm[i]);
  float D = 0.f;
#pragma unroll
  for (int i = 0; i < 16; ++i) D += ss[i] * __expf(sm[i] - M);
  float alpha = __expf(sm[blk] - M) / D;

  int wave = tid >> 6, lane = tid & 63, q4 = lane >> 4, l16 = lane & 15;
  int rbase = wave * 4 + q4;
  const f4 vn = ((const f4*)(vnew + bh * HDIM))[l16];
  size_t base = ((size_t)bh * SKV + j0 + rbase) * 16 + l16;
  const f4* V4 = (const f4*)cacheV + base;
  f4* O4 = (f4*)outV + base;
  f4 acc = (f4)0.f;
#pragma unroll
  for (int t = 0; t < 16; ++t) {
    int j = j0 + rbase + t * 16;
    f4 vv = V4[t * 256];                       // plain load
    if (j == lp) vv = vn;
    __builtin_nontemporal_store(vv, &O4[t * 256]);
    acc += sp[rbase + t * 16] * vv;
  }
  acc.x += __shfl_xor(acc.x, 16); acc.x += __shfl_xor(acc.x, 32);
  acc.y += __shfl_xor(acc.y, 16); acc.y += __shfl_xor(acc.y, 32);
  acc.z += __shfl_xor(acc.z, 16); acc.z += __shfl_xor(acc.z, 32);
  acc.w += __shfl_xor(acc.w, 16); acc.w += __shfl_xor(acc.w, 32);
  if (q4 == 0) ((f4*)part[wave])[l16] = acc;
  __syncthreads();
  if (tid < 64) {
    prec[(size_t)blockIdx.x * HDIM + tid] =
        alpha * (part[0][tid] + part[1][tid] + part[2][tid] + part[3][tid]);
  }
}

// ---------------------------------------------------------------------------
// Wo GEMM; x-staging sums the 16 per-strip records for bh=(b,h).
// grid (2, 32 heads), block 256.
// ---------------------------------------------------------------------------
__global__ __launch_bounds__(256) void attn_gemm_part(
    const float* __restrict__ prec, const float* __restrict__ Wo,
    float* __restrict__ po) {
  __shared__ float xs[16][64];
  int tid = threadIdx.x;
  int h = blockIdx.y;
  {
    int g = tid >> 4, u = tid & 15;        // g = batch, u = dim quad
    const float* r = prec + (size_t)(g * NHEAD + h) * NSTRIP * HDIM + u * 4;
    f4 a = (f4)0.f;
#pragma unroll
    for (int s = 0; s < 16; ++s) a += *(const f4*)&r[s * HDIM];
    *(f4*)&xs[g][u * 4] = a;
  }
  __syncthreads();
  int o = blockIdx.x * 1024 + tid * 4;
  int i0 = h * 64;
  f4 acc[16];
#pragma unroll
  for (int b = 0; b < 16; ++b) acc[b] = (f4)0.f;
#pragma unroll 8
  for (int i = 0; i < 64; ++i) {
    f4 w = *(const f4*)&Wo[(size_t)(i0 + i) * DMODEL + o];
#pragma unroll
    for (int b = 0; b < 16; ++b) acc[b] += xs[b][i] * w;
  }
  float* p = po + (size_t)blockIdx.y * (16 * DMODEL) + o;
#pragma unroll
  for (int b = 0; b < 16; ++b) *(f4*)&p[b * DMODEL] = acc[b];
}

// ---------------------------------------------------------------------------
extern "C" void kernel_launch(void* const* d_in, const int* in_sizes, int n_in,
                              void* d_out, int out_size, void* d_ws, size_t ws_size,
                              hipStream_t stream) {
  const float* x        = (const float*)d_in[0];
  const int*   last_pos = (const int*)d_in[1];
  // d_in[2] = mask (recomputed from last_pos, ignored)
  const float* Wq = (const float*)d_in[3];
  const float* bq = (const float*)d_in[4];
  const float* Wk = (const float*)d_in[5];
  const float* bk = (const float*)d_in[6];
  const float* Wv = (const float*)d_in[7];
  const float* bv = (const float*)d_in[8];
  const float* Wo = (const float*)d_in[9];
  const float* bo = (const float*)d_in[10];
  const float* cacheK = (const float*)d_in[11];
  const float* cacheV = (const float*)d_in[12];

  float* out  = (float*)d_out;                      // 32768
  float* outK = out + (size_t)BB * DMODEL;
  float* outV = outK + (size_t)BH * SKV * HDIM;

  float* ws    = (float*)d_ws;
  float* q     = ws;                                // 32768
  float* k     = ws + 32768;
  float* v     = ws + 65536;
  float* pstat = ws + 98304;                        // 512*16*2 = 16384
  float* prec  = ws + 114688;                       // 8192*64 = 524288
  float* big   = ws + 114688 + 524288;              // 3x1048576 region
  float* pq = big;
  float* pk = big + 1048576;
  float* pv = big + 2097152;
  float* scores = big;                              // reuse after gemm_reduce
  float* po = big + 1048576;                        // distinct from scores

  gemm_part<<<dim3(2, 32, 3), 256, 0, stream>>>(x, Wq, Wk, Wv, pq, pk, pv);
  gemm_reduce<<<dim3(128, 3), 256, 0, stream>>>(pq, pk, pv, bq, bk, bv, q, k, v);
  k_copy_scores<<<8192, 256, 0, stream>>>(cacheK, k, q, last_pos, outK, scores, pstat);
  v_copy_pv<<<8192, 256, 0, stream>>>(cacheV, v, scores, pstat, last_pos, outV, prec);
  attn_gemm_part<<<dim3(2, 32), 256, 0, stream>>>(prec, Wo, po);
  gemm_reduce<<<dim3(128, 1), 256, 0, stream>>>(po, po, po, bo, bo, bo, out, out, out);
}

// Round 12
// 424.662 us; speedup vs baseline: 1.1709x; 1.1709x over previous
//
#include <hip/hip_runtime.h>
#include <math.h>

#define BB 16
#define DMODEL 2048
#define NHEAD 32
#define SKV 4096
#define HDIM 64
#define BH (BB*NHEAD)   /* 512 */
#define NSTRIP 8        /* 512-row strips per (b,h) */

typedef float f4 __attribute__((ext_vector_type(4)));

// ---------------------------------------------------------------------------
// partial GEMM: part[tile_y][b][o] = sum_{i in tile of 64} src[b][i]*W[i][o]
// grid (2, 32, nmat), block 256, thread owns 4 consecutive o-columns.
// ---------------------------------------------------------------------------
__global__ __launch_bounds__(256) void gemm_part(
    const float* __restrict__ src,
    const float* __restrict__ Wa, const float* __restrict__ Wb,
    const float* __restrict__ Wc,
    float* __restrict__ pa, float* __restrict__ pb, float* __restrict__ pc) {
  const float* W = (blockIdx.z == 0) ? Wa : ((blockIdx.z == 1) ? Wb : Wc);
  float* part    = (blockIdx.z == 0) ? pa : ((blockIdx.z == 1) ? pb : pc);
  __shared__ float xs[16][64];
  int tid = threadIdx.x;
  int i0 = blockIdx.y * 64;
  int o  = blockIdx.x * 1024 + tid * 4;
  {
    int t = tid * 4;
    int b = t >> 6, i = t & 63;
    *(f4*)&xs[b][i] = *(const f4*)&src[b * DMODEL + i0 + i];
  }
  __syncthreads();
  f4 acc[16];
#pragma unroll
  for (int b = 0; b < 16; ++b) acc[b] = (f4)0.f;
#pragma unroll 8
  for (int i = 0; i < 64; ++i) {
    f4 w = *(const f4*)&W[(size_t)(i0 + i) * DMODEL + o];
#pragma unroll
    for (int b = 0; b < 16; ++b) acc[b] += xs[b][i] * w;
  }
  float* p = part + (size_t)blockIdx.y * (16 * DMODEL) + o;
#pragma unroll
  for (int b = 0; b < 16; ++b) *(f4*)&p[b * DMODEL] = acc[b];
}

// ---------------------------------------------------------------------------
// reduce partials over 32 tiles + bias -> dst.  grid (128, nmat)
// ---------------------------------------------------------------------------
__global__ __launch_bounds__(256) void gemm_reduce(
    const float* __restrict__ pa, const float* __restrict__ pb,
    const float* __restrict__ pc,
    const float* __restrict__ ba, const float* __restrict__ bb,
    const float* __restrict__ bc,
    float* __restrict__ da, float* __restrict__ db, float* __restrict__ dc) {
  const float* p    = (blockIdx.y == 0) ? pa : ((blockIdx.y == 1) ? pb : pc);
  const float* bias = (blockIdx.y == 0) ? ba : ((blockIdx.y == 1) ? bb : bc);
  float* dst        = (blockIdx.y == 0) ? da : ((blockIdx.y == 1) ? db : dc);
  int idx = blockIdx.x * 256 + threadIdx.x;
  float s = bias[idx & (DMODEL - 1)];
#pragma unroll 8
  for (int t = 0; t < 32; ++t) s += p[(size_t)t * (16 * DMODEL) + idx];
  dst[idx] = s;
}

// ---------------------------------------------------------------------------
// K copy + scores. 512 threads (8 waves) x 512 rows per block; 16-deep nt
// stream loop per wave (unchanged depth, half the blocks vs R9).
// Stores UNNORMALIZED probs exp(s - M_strip) via LDS (coalesced), per-strip
// (M, Sexp) to pstat. q pre-scaled by 1/8. nt/nt hints (A/B-proven).
// ---------------------------------------------------------------------------
__global__ __launch_bounds__(512) void k_copy_scores(
    const float* __restrict__ cacheK, const float* __restrict__ knew,
    const float* __restrict__ qv, const int* __restrict__ last_pos,
    float* __restrict__ outK, float* __restrict__ scores,
    float* __restrict__ pstat) {
  int bh = blockIdx.x >> 3;
  int blk = blockIdx.x & 7;
  int j0 = blk << 9;                 // 512 rows per block
  int b = bh >> 5;
  int lp = last_pos[b];
  int tid = threadIdx.x;
  int wave = tid >> 6, lane = tid & 63, q4 = lane >> 4, l16 = lane & 15;
  int rbase = wave * 4 + q4;         // 0..31
  const f4 qf = ((const f4*)(qv + bh * HDIM))[l16] * 0.125f;
  const f4 kn = ((const f4*)(knew + bh * HDIM))[l16];
  size_t base = ((size_t)bh * SKV + j0 + rbase) * 16 + l16;
  const f4* K4 = (const f4*)cacheK + base;
  f4* O4 = (f4*)outK + base;
  float fv[16];
#pragma unroll
  for (int t = 0; t < 16; ++t) {
    int j = j0 + rbase + t * 32;
    f4 kv = __builtin_nontemporal_load(&K4[t * 512]);
    if (j == lp) kv = kn;
    __builtin_nontemporal_store(kv, &O4[t * 512]);
    float p = qf.x * kv.x + qf.y * kv.y + qf.z * kv.z + qf.w * kv.w;
    p += __shfl_xor(p, 1);
    p += __shfl_xor(p, 2);
    p += __shfl_xor(p, 4);
    p += __shfl_xor(p, 8);
    fv[t] = (j <= lp) ? p : -1e30f;
  }
  float m = fv[0];
#pragma unroll
  for (int t = 1; t < 16; ++t) m = fmaxf(m, fv[t]);
  m = fmaxf(m, __shfl_xor(m, 16));
  m = fmaxf(m, __shfl_xor(m, 32));
  __shared__ float lm[8], ls[8], sp[512];
  if (lane == 0) lm[wave] = m;
  __syncthreads();
  float M = lm[0];
#pragma unroll
  for (int i = 1; i < 8; ++i) M = fmaxf(M, lm[i]);
  float se = 0.f;
#pragma unroll
  for (int t = 0; t < 16; ++t) {
    float e = __expf(fv[t] - M);
    se += e;
    if (l16 == 0) sp[rbase + t * 32] = e;   // 0 for masked rows
  }
  se += __shfl_xor(se, 16);
  se += __shfl_xor(se, 32);
  if (lane == 0) ls[wave] = se;
  __syncthreads();
  scores[(size_t)bh * SKV + j0 + tid] = sp[tid];   // coalesced 2KB store
  if (tid == 0) {
    float S = 0.f;
#pragma unroll
    for (int i = 0; i < 8; ++i) S += ls[i];
    pstat[(bh * NSTRIP + blk) * 2 + 0] = M;
    pstat[(bh * NSTRIP + blk) * 2 + 1] = S;
  }
}

// ---------------------------------------------------------------------------
// V copy + PV accumulate. 512 threads x 512 rows. Cheap prelude (no
// per-element exp): stage unnormalized probs in LDS + one scalar alpha.
// Per-strip record = alpha * sum (no atomics). nt/nt hints.
// ---------------------------------------------------------------------------
__global__ __launch_bounds__(512) void v_copy_pv(
    const float* __restrict__ cacheV, const float* __restrict__ vnew,
    const float* __restrict__ scores, const float* __restrict__ pstat,
    const int* __restrict__ last_pos,
    float* __restrict__ outV, float* __restrict__ prec) {
  __shared__ float sm[8], ss[8], sp[512];
  __shared__ float part[8][64];
  int bh = blockIdx.x >> 3;
  int blk = blockIdx.x & 7;
  int j0 = blk << 9;
  int b = bh >> 5;
  int lp = last_pos[b];
  int tid = threadIdx.x;
  if (tid < 8) {
    sm[tid] = pstat[(bh * NSTRIP + tid) * 2 + 0];
    ss[tid] = pstat[(bh * NSTRIP + tid) * 2 + 1];
  }
  sp[tid] = scores[(size_t)bh * SKV + j0 + tid];   // unnormalized probs
  __syncthreads();
  float M = sm[0];
#pragma unroll
  for (int i = 1; i < 8; ++i) M = fmaxf(M, sm[i]);
  float D = 0.f;
#pragma unroll
  for (int i = 0; i < 8; ++i) D += ss[i] * __expf(sm[i] - M);
  float alpha = __expf(sm[blk] - M) / D;

  int wave = tid >> 6, lane = tid & 63, q4 = lane >> 4, l16 = lane & 15;
  int rbase = wave * 4 + q4;
  const f4 vn = ((const f4*)(vnew + bh * HDIM))[l16];
  size_t base = ((size_t)bh * SKV + j0 + rbase) * 16 + l16;
  const f4* V4 = (const f4*)cacheV + base;
  f4* O4 = (f4*)outV + base;
  f4 acc = (f4)0.f;
#pragma unroll
  for (int t = 0; t < 16; ++t) {
    int j = j0 + rbase + t * 32;
    f4 vv = __builtin_nontemporal_load(&V4[t * 512]);
    if (j == lp) vv = vn;
    __builtin_nontemporal_store(vv, &O4[t * 512]);
    acc += sp[rbase + t * 32] * vv;
  }
  acc.x += __shfl_xor(acc.x, 16); acc.x += __shfl_xor(acc.x, 32);
  acc.y += __shfl_xor(acc.y, 16); acc.y += __shfl_xor(acc.y, 32);
  acc.z += __shfl_xor(acc.z, 16); acc.z += __shfl_xor(acc.z, 32);
  acc.w += __shfl_xor(acc.w, 16); acc.w += __shfl_xor(acc.w, 32);
  if (q4 == 0) ((f4*)part[wave])[l16] = acc;
  __syncthreads();
  if (tid < 64) {
    float s = part[0][tid];
#pragma unroll
    for (int w = 1; w < 8; ++w) s += part[w][tid];
    prec[(size_t)blockIdx.x * HDIM + tid] = alpha * s;
  }
}

// ---------------------------------------------------------------------------
// Wo GEMM; x-staging sums the NSTRIP per-strip records for bh=(b,h).
// grid (2, 32 heads), block 256.
// ---------------------------------------------------------------------------
__global__ __launch_bounds__(256) void attn_gemm_part(
    const float* __restrict__ prec, const float* __restrict__ Wo,
    float* __restrict__ po) {
  __shared__ float xs[16][64];
  int tid = threadIdx.x;
  int h = blockIdx.y;
  {
    int g = tid >> 4, u = tid & 15;        // g = batch, u = dim quad
    const float* r = prec + (size_t)(g * NHEAD + h) * NSTRIP * HDIM + u * 4;
    f4 a = (f4)0.f;
#pragma unroll
    for (int s = 0; s < NSTRIP; ++s) a += *(const f4*)&r[s * HDIM];
    *(f4*)&xs[g][u * 4] = a;
  }
  __syncthreads();
  int o = blockIdx.x * 1024 + tid * 4;
  int i0 = h * 64;
  f4 acc[16];
#pragma unroll
  for (int b = 0; b < 16; ++b) acc[b] = (f4)0.f;
#pragma unroll 8
  for (int i = 0; i < 64; ++i) {
    f4 w = *(const f4*)&Wo[(size_t)(i0 + i) * DMODEL + o];
#pragma unroll
    for (int b = 0; b < 16; ++b) acc[b] += xs[b][i] * w;
  }
  float* p = po + (size_t)blockIdx.y * (16 * DMODEL) + o;
#pragma unroll
  for (int b = 0; b < 16; ++b) *(f4*)&p[b * DMODEL] = acc[b];
}

// ---------------------------------------------------------------------------
extern "C" void kernel_launch(void* const* d_in, const int* in_sizes, int n_in,
                              void* d_out, int out_size, void* d_ws, size_t ws_size,
                              hipStream_t stream) {
  const float* x        = (const float*)d_in[0];
  const int*   last_pos = (const int*)d_in[1];
  // d_in[2] = mask (recomputed from last_pos, ignored)
  const float* Wq = (const float*)d_in[3];
  const float* bq = (const float*)d_in[4];
  const float* Wk = (const float*)d_in[5];
  const float* bk = (const float*)d_in[6];
  const float* Wv = (const float*)d_in[7];
  const float* bv = (const float*)d_in[8];
  const float* Wo = (const float*)d_in[9];
  const float* bo = (const float*)d_in[10];
  const float* cacheK = (const float*)d_in[11];
  const float* cacheV = (const float*)d_in[12];

  float* out  = (float*)d_out;                      // 32768
  float* outK = out + (size_t)BB * DMODEL;
  float* outV = outK + (size_t)BH * SKV * HDIM;

  float* ws    = (float*)d_ws;
  float* q     = ws;                                // 32768
  float* k     = ws + 32768;
  float* v     = ws + 65536;
  float* pstat = ws + 98304;                        // 512*8*2 = 8192
  float* prec  = ws + 106496;                       // 4096*64 = 262144
  float* big   = ws + 106496 + 262144;              // 3x1048576 region
  float* pq = big;
  float* pk = big + 1048576;
  float* pv = big + 2097152;
  float* scores = big;                              // reuse after gemm_reduce
  float* po = big + 1048576;                        // distinct from scores

  gemm_part<<<dim3(2, 32, 3), 256, 0, stream>>>(x, Wq, Wk, Wv, pq, pk, pv);
  gemm_reduce<<<dim3(128, 3), 256, 0, stream>>>(pq, pk, pv, bq, bk, bv, q, k, v);
  k_copy_scores<<<4096, 512, 0, stream>>>(cacheK, k, q, last_pos, outK, scores, pstat);
  v_copy_pv<<<4096, 512, 0, stream>>>(cacheV, v, scores, pstat, last_pos, outV, prec);
  attn_gemm_part<<<dim3(2, 32), 256, 0, stream>>>(prec, Wo, po);
  gemm_reduce<<<dim3(128, 1), 256, 0, stream>>>(po, po, po, bo, bo, bo, out, out, out);
}